// Round 3
// baseline (957.643 us; speedup 1.0000x reference)
//
#include <hip/hip_runtime.h>
#include <cstdint>

#define B_SZ 4096
#define T_SZ 1000
#define I_SZ 3
#define H_SZ 10
#define GPW  2          // batch groups per wave (10 lanes each; rest are dummy groups).
                        // GPW=2 -> 2048 single-wave blocks -> 2 waves/SIMD: the wave's
                        // ~1100 cyc/iter of exposed latency (ds_read ~120cy, trans
                        // chains) is covered by the co-resident wave. Instruction count
                        // per wave is lane-count-independent, so extra waves are free
                        // until the 2-cyc/instr issue floor (~800 cyc per SIMD per pair).
#define GRP_STRIDE 40   // words per group slot in LDS (160B, 16B-aligned)

__device__ __forceinline__ float fsig(float s) {
    // sigmoid(s) = 1/(1+e^-s); inf-safe: s<<0 -> e=inf -> rcp=0; s>>0 -> e=0 -> 1
    float e = __expf(-s);
    return __builtin_amdgcn_rcpf(1.0f + e);
}
__device__ __forceinline__ float ftanh(float y) {
    // tanh(y) = 1 - 2/(e^{2y}+1); inf-safe at both ends (no inf*0)
    float e2 = __expf(y + y);
    return 1.0f - 2.0f * __builtin_amdgcn_rcpf(e2 + 1.0f);
}

// acc += dot(W[g_][0:10], {v0.xyzw, v1.xyzw, v2.xy})
#define DOT10(W, g_, v0, v1, v2, acc) do { \
    acc = fmaf(W[g_][0], (v0).x, acc); \
    acc = fmaf(W[g_][1], (v0).y, acc); \
    acc = fmaf(W[g_][2], (v0).z, acc); \
    acc = fmaf(W[g_][3], (v0).w, acc); \
    acc = fmaf(W[g_][4], (v1).x, acc); \
    acc = fmaf(W[g_][5], (v1).y, acc); \
    acc = fmaf(W[g_][6], (v1).z, acc); \
    acc = fmaf(W[g_][7], (v1).w, acc); \
    acc = fmaf(W[g_][8], (v2).x, acc); \
    acc = fmaf(W[g_][9], (v2).y, acc); \
} while (0)

__global__ __launch_bounds__(64, 1) void gru3_fused(
    const float* __restrict__ x,
    const float* __restrict__ Wih0, const float* __restrict__ Whh0,
    const float* __restrict__ bih0, const float* __restrict__ bhh0,
    const float* __restrict__ Wih1, const float* __restrict__ Whh1,
    const float* __restrict__ bih1, const float* __restrict__ bhh1,
    const float* __restrict__ Wih2, const float* __restrict__ Whh2,
    const float* __restrict__ bih2, const float* __restrict__ bhh2,
    const float* __restrict__ Wout, const float* __restrict__ bout,
    float* __restrict__ out)
{
    __shared__ __align__(16) float lds[7 * GRP_STRIDE];

    const int lane  = threadIdx.x;     // block = 1 wave of 64
    const int j     = lane % H_SZ;     // hidden unit 0..9
    const int g     = lane / H_SZ;     // group 0..6 (g >= GPW are dummy, never store out)
    const int b_raw = blockIdx.x * GPW + g;
    const int b     = b_raw < B_SZ ? b_raw : (B_SZ - 1);

    // ---- weights for this lane's unit j, all in registers ----
    float wi0[3][I_SZ], wh0[3][H_SZ];
    float wi1[3][H_SZ], wh1[3][H_SZ];
    float wi2[3][H_SZ], wh2[3][H_SZ];
#pragma unroll
    for (int gg = 0; gg < 3; ++gg) {
        const int row = gg * H_SZ + j;
#pragma unroll
        for (int i = 0; i < I_SZ; ++i) wi0[gg][i] = Wih0[row * I_SZ + i];
#pragma unroll
        for (int k = 0; k < H_SZ; ++k) wh0[gg][k] = Whh0[row * H_SZ + k];
#pragma unroll
        for (int k = 0; k < H_SZ; ++k) wi1[gg][k] = Wih1[row * H_SZ + k];
#pragma unroll
        for (int k = 0; k < H_SZ; ++k) wh1[gg][k] = Whh1[row * H_SZ + k];
#pragma unroll
        for (int k = 0; k < H_SZ; ++k) wi2[gg][k] = Wih2[row * H_SZ + k];
#pragma unroll
        for (int k = 0; k < H_SZ; ++k) wh2[gg][k] = Whh2[row * H_SZ + k];
    }
    // biases: r,z get combined (bih+bhh); n keeps them separate (bhh_n is scaled by r)
    const float br0 = bih0[j] + bhh0[j], bz0 = bih0[H_SZ + j] + bhh0[H_SZ + j];
    const float bni0 = bih0[2 * H_SZ + j], bnh0 = bhh0[2 * H_SZ + j];
    const float br1 = bih1[j] + bhh1[j], bz1 = bih1[H_SZ + j] + bhh1[H_SZ + j];
    const float bni1 = bih1[2 * H_SZ + j], bnh1 = bhh1[2 * H_SZ + j];
    const float br2 = bih2[j] + bhh2[j], bz2 = bih2[H_SZ + j] + bhh2[H_SZ + j];
    const float bni2 = bih2[2 * H_SZ + j], bnh2 = bhh2[2 * H_SZ + j];

    const int gb = g * GRP_STRIDE;
    // init h = 0 (words 10,11 of each 12-word layer slot are read as float4 tails
    // but never used in the dot products)
    lds[gb + j]      = 0.0f;
    lds[gb + 12 + j] = 0.0f;
    lds[gb + 24 + j] = 0.0f;
    float h0 = 0.0f, h1 = 0.0f, h2 = 0.0f;   // this lane's own elements

    const float* xp = x + (size_t)b * (T_SZ * I_SZ);

    // x software-prefetch: registers hold x[t] for the CURRENT iteration while
    // the loads for t+1 are in flight underneath the layer bodies.
    float cx0 = xp[0], cx1 = xp[1], cx2 = xp[2];

    const float4* pa = reinterpret_cast<const float4*>(&lds[gb]);
    const float4* pb = reinterpret_cast<const float4*>(&lds[gb + 12]);
    const float4* pc = reinterpret_cast<const float4*>(&lds[gb + 24]);

    // h-vector registers, rotated at loop bottom: reads of the NEXT iteration's
    // inputs are issued right after this iteration's ds_writes (same-wave DS ops
    // are ordered -> RAW through LDS is safe, block = 1 wave so no barrier), so
    // ds_read issue+latency overlaps the loop tail instead of heading the body.
    float4 A0 = pa[0], A1 = pa[1], A2 = pa[2];          // h0(it-1)
    float4 B0 = pb[0], B1 = pb[1], B2 = pb[2];          // h1(it-2)
    float4 C0 = pc[0], C1 = pc[1], C2 = pc[2];          // h2(it-3)

    // Layer-pipelined: iter it computes L0@step it, L1@step it-1, L2@step it-2.
#pragma unroll 1
    for (int it = 0; it < T_SZ + 2; ++it) {
        const float x0 = cx0, x1 = cx1, x2 = cx2;
        const int tn = (it + 1 < T_SZ) ? it + 1 : (T_SZ - 1);     // clamp: no OOB
        cx0 = xp[tn * 3 + 0];
        cx1 = xp[tn * 3 + 1];
        cx2 = xp[tn * 3 + 2];

        if (it < T_SZ) {                       // ---- layer 0, step it ----
            float ar = br0, az = bz0, axn = bni0, ahn = bnh0;
            ar  = fmaf(wi0[0][0], x0, ar);  ar  = fmaf(wi0[0][1], x1, ar);  ar  = fmaf(wi0[0][2], x2, ar);
            az  = fmaf(wi0[1][0], x0, az);  az  = fmaf(wi0[1][1], x1, az);  az  = fmaf(wi0[1][2], x2, az);
            axn = fmaf(wi0[2][0], x0, axn); axn = fmaf(wi0[2][1], x1, axn); axn = fmaf(wi0[2][2], x2, axn);
            DOT10(wh0, 0, A0, A1, A2, ar);
            DOT10(wh0, 1, A0, A1, A2, az);
            DOT10(wh0, 2, A0, A1, A2, ahn);
            const float r = fsig(ar), z = fsig(az);
            const float n = ftanh(fmaf(r, ahn, axn));
            h0 = fmaf(z, h0 - n, n);           // (1-z)n + z h
            lds[gb + j] = h0;
        }
        if (it >= 1 && it <= T_SZ) {           // ---- layer 1, step it-1, input A ----
            float ar = br1, az = bz1, axn = bni1, ahn = bnh1;
            DOT10(wi1, 0, A0, A1, A2, ar);
            DOT10(wi1, 1, A0, A1, A2, az);
            DOT10(wi1, 2, A0, A1, A2, axn);
            DOT10(wh1, 0, B0, B1, B2, ar);
            DOT10(wh1, 1, B0, B1, B2, az);
            DOT10(wh1, 2, B0, B1, B2, ahn);
            const float r = fsig(ar), z = fsig(az);
            const float n = ftanh(fmaf(r, ahn, axn));
            h1 = fmaf(z, h1 - n, n);
            lds[gb + 12 + j] = h1;
        }
        if (it >= 2) {                         // ---- layer 2, step it-2, input B ----
            float ar = br2, az = bz2, axn = bni2, ahn = bnh2;
            DOT10(wi2, 0, B0, B1, B2, ar);
            DOT10(wi2, 1, B0, B1, B2, az);
            DOT10(wi2, 2, B0, B1, B2, axn);
            DOT10(wh2, 0, C0, C1, C2, ar);
            DOT10(wh2, 1, C0, C1, C2, az);
            DOT10(wh2, 2, C0, C1, C2, ahn);
            const float r = fsig(ar), z = fsig(az);
            const float n = ftanh(fmaf(r, ahn, axn));
            h2 = fmaf(z, h2 - n, n);
            lds[gb + 24 + j] = h2;
        }

        // rotate: issue next iteration's h reads under the loop tail
        A0 = pa[0]; A1 = pa[1]; A2 = pa[2];
        B0 = pb[0]; B1 = pb[1]; B2 = pb[2];
        C0 = pc[0]; C1 = pc[1]; C2 = pc[2];
    }

    // ---- output projection: out[b] = h2(T-1) . Wout + bout ----
    if (j == 0 && g < GPW && b_raw < B_SZ) {
        const float* hv = &lds[gb + 24];
        float acc = bout[0];
#pragma unroll
        for (int k = 0; k < H_SZ; ++k) acc = fmaf(hv[k], Wout[k], acc);
        out[b_raw] = acc;
    }
}

extern "C" void kernel_launch(void* const* d_in, const int* in_sizes, int n_in,
                              void* d_out, int out_size, void* d_ws, size_t ws_size,
                              hipStream_t stream) {
    const float* x    = (const float*)d_in[0];
    const float* Wih0 = (const float*)d_in[1];
    const float* Whh0 = (const float*)d_in[2];
    const float* bih0 = (const float*)d_in[3];
    const float* bhh0 = (const float*)d_in[4];
    const float* Wih1 = (const float*)d_in[5];
    const float* Whh1 = (const float*)d_in[6];
    const float* bih1 = (const float*)d_in[7];
    const float* bhh1 = (const float*)d_in[8];
    const float* Wih2 = (const float*)d_in[9];
    const float* Whh2 = (const float*)d_in[10];
    const float* bih2 = (const float*)d_in[11];
    const float* bhh2 = (const float*)d_in[12];
    const float* Wout = (const float*)d_in[13];
    const float* bout = (const float*)d_in[14];
    float* out = (float*)d_out;

    const int grid = (B_SZ + GPW - 1) / GPW;   // 2048 blocks x 1 wave -> 2 waves/SIMD
    gru3_fused<<<grid, 64, 0, stream>>>(x, Wih0, Whh0, bih0, bhh0,
                                        Wih1, Whh1, bih1, bhh1,
                                        Wih2, Whh2, bih2, bhh2,
                                        Wout, bout, out);
}

// Round 4
// 616.724 us; speedup vs baseline: 1.5528x; 1.5528x over previous
//
#include <hip/hip_runtime.h>
#include <cstdint>

#define B_SZ 4096
#define T_SZ 1000
#define I_SZ 3
#define H_SZ 10
#define GPW  6          // batch groups per wave (10 lanes each; lanes 60-63 dummy)
#define NGRP 7          // 6 real + 1 dummy group
#define SLOT 12         // words per group h-slot (48B; float4-aligned)
#define PLANE (NGRP * SLOT)   // 84 words per (buf, layer) plane

// Bank math: per ds_read_b128 at float4 index q, lane group g reads words
// g*12 + 4q .. +3 -> bank starts {0,12,24,4,16,28,8} (12g mod 32), all
// disjoint 4-bank ranges -> ZERO read conflicts (old stride-40 layout aliased).

__device__ __forceinline__ float fsig(float s) {
    float e = __expf(-s);                       // s<<0 -> inf -> rcp 0; s>>0 -> 1
    return __builtin_amdgcn_rcpf(1.0f + e);
}
__device__ __forceinline__ float ftanh(float y) {
    float e2 = __expf(y + y);                   // inf-safe both ends
    return 1.0f - 2.0f * __builtin_amdgcn_rcpf(e2 + 1.0f);
}

// acc += dot(W[g_][0:10], {v0.xyzw, v1.xyzw, v2.xy})
#define DOT10(W, g_, v0, v1, v2, acc) do { \
    acc = fmaf(W[g_][0], (v0).x, acc); \
    acc = fmaf(W[g_][1], (v0).y, acc); \
    acc = fmaf(W[g_][2], (v0).z, acc); \
    acc = fmaf(W[g_][3], (v0).w, acc); \
    acc = fmaf(W[g_][4], (v1).x, acc); \
    acc = fmaf(W[g_][5], (v1).y, acc); \
    acc = fmaf(W[g_][6], (v1).z, acc); \
    acc = fmaf(W[g_][7], (v1).w, acc); \
    acc = fmaf(W[g_][8], (v2).x, acc); \
    acc = fmaf(W[g_][9], (v2).y, acc); \
} while (0)

// 3 waves per block: wave w computes layer w for all 6 batch groups.
// Layer-pipelined: iter it -> L0@t=it, L1@t=it-1, L2@t=it-2. All reads hit the
// buffer written LAST iteration (double-buffered by it&1), so ONE barrier per
// iteration is sufficient (it orders prev writes before this iter's reads, and
// all prev reads before this iter's writes to the other buffer).
__global__ __launch_bounds__(192) void gru3_waves(
    const float* __restrict__ x,
    const float* __restrict__ Wih0, const float* __restrict__ Whh0,
    const float* __restrict__ bih0, const float* __restrict__ bhh0,
    const float* __restrict__ Wih1, const float* __restrict__ Whh1,
    const float* __restrict__ bih1, const float* __restrict__ bhh1,
    const float* __restrict__ Wih2, const float* __restrict__ Whh2,
    const float* __restrict__ bih2, const float* __restrict__ bhh2,
    const float* __restrict__ Wout, const float* __restrict__ bout,
    float* __restrict__ out)
{
    __shared__ __align__(16) float lds[2][3][PLANE];

    const int tid  = threadIdx.x;
    const int w    = tid >> 6;        // 0,1,2 = layer this wave owns
    const int lane = tid & 63;
    const int j    = lane % H_SZ;     // hidden unit 0..9
    const int g    = lane / H_SZ;     // group 0..6 (6 = dummy)
    const int b_raw = blockIdx.x * GPW + g;
    const int b     = b_raw < B_SZ ? b_raw : (B_SZ - 1);

    // ---- this wave's layer weights in registers (unified 10-wide layout) ----
    const float* Wih = (w == 0) ? Wih0 : (w == 1) ? Wih1 : Wih2;
    const float* Whh = (w == 0) ? Whh0 : (w == 1) ? Whh1 : Whh2;
    const float* bih = (w == 0) ? bih0 : (w == 1) ? bih1 : bih2;
    const float* bhh = (w == 0) ? bhh0 : (w == 1) ? bhh1 : bhh2;
    const int in_dim = (w == 0) ? I_SZ : H_SZ;

    float wi[3][H_SZ], wh[3][H_SZ];
#pragma unroll
    for (int gg = 0; gg < 3; ++gg) {
        const int row = gg * H_SZ + j;
#pragma unroll
        for (int k = 0; k < H_SZ; ++k) wh[gg][k] = Whh[row * H_SZ + k];
#pragma unroll
        for (int k = 0; k < H_SZ; ++k)
            wi[gg][k] = (k < in_dim) ? Wih[row * in_dim + k] : 0.0f;
    }
    const float br  = bih[j] + bhh[j];
    const float bz  = bih[H_SZ + j] + bhh[H_SZ + j];
    const float bni = bih[2 * H_SZ + j];
    const float bnh = bhh[2 * H_SZ + j];

    // zero both h buffers (all planes)
    for (int i = tid; i < 2 * 3 * PLANE; i += 192) (&lds[0][0][0])[i] = 0.0f;

    float h = 0.0f;                    // this lane's own h element for layer w
    const float* xp = x + (size_t)b * (T_SZ * I_SZ);
    float cx0 = 0.f, cx1 = 0.f, cx2 = 0.f;
    if (w == 0) { cx0 = xp[0]; cx1 = xp[1]; cx2 = xp[2]; }   // x prefetch

    const int gb = g * SLOT;

#pragma unroll 1
    for (int it = 0; it < T_SZ + 2; ++it) {
        __syncthreads();               // prev-iter writes visible; WAR-safe (dbuf)
        const int wr = it & 1, rd = wr ^ 1;
        const bool active = (w == 0) ? (it < T_SZ)
                          : (w == 1) ? (it >= 1 && it <= T_SZ)
                                     : (it >= 2);
        if (active) {                  // wave-uniform branch
            float ar = br, az = bz, axn = bni, ahn = bnh;

            const float4* ph = reinterpret_cast<const float4*>(&lds[rd][w][gb]);
            const float4 H0 = ph[0], H1 = ph[1], H2 = ph[2];   // own h(t-1)

            if (w == 0) {
                const float x0 = cx0, x1 = cx1, x2 = cx2;
                const int tn = (it + 1 < T_SZ) ? it + 1 : (T_SZ - 1);
                cx0 = xp[tn * 3 + 0];  // prefetch next under this body
                cx1 = xp[tn * 3 + 1];
                cx2 = xp[tn * 3 + 2];
                ar  = fmaf(wi[0][0], x0, ar);  ar  = fmaf(wi[0][1], x1, ar);  ar  = fmaf(wi[0][2], x2, ar);
                az  = fmaf(wi[1][0], x0, az);  az  = fmaf(wi[1][1], x1, az);  az  = fmaf(wi[1][2], x2, az);
                axn = fmaf(wi[2][0], x0, axn); axn = fmaf(wi[2][1], x1, axn); axn = fmaf(wi[2][2], x2, axn);
            } else {
                const float4* pi = reinterpret_cast<const float4*>(&lds[rd][w - 1][gb]);
                const float4 I0 = pi[0], I1 = pi[1], I2 = pi[2]; // input = prev layer h
                DOT10(wi, 0, I0, I1, I2, ar);
                DOT10(wi, 1, I0, I1, I2, az);
                DOT10(wi, 2, I0, I1, I2, axn);
            }
            DOT10(wh, 0, H0, H1, H2, ar);
            DOT10(wh, 1, H0, H1, H2, az);
            DOT10(wh, 2, H0, H1, H2, ahn);

            const float r = fsig(ar), z = fsig(az);
            const float n = ftanh(fmaf(r, ahn, axn));
            h = fmaf(z, h - n, n);                 // (1-z)n + z h
            lds[wr][w][gb + j] = h;
        }
    }

    __syncthreads();
    // ---- output projection from h2(T-1), written at it=T+1 into buf (T+1)&1 ----
    if (w == 2 && j == 0 && g < GPW && b_raw < B_SZ) {
        const float* hv = &lds[(T_SZ + 1) & 1][2][gb];
        float acc = bout[0];
#pragma unroll
        for (int k = 0; k < H_SZ; ++k) acc = fmaf(hv[k], Wout[k], acc);
        out[b_raw] = acc;
    }
}

extern "C" void kernel_launch(void* const* d_in, const int* in_sizes, int n_in,
                              void* d_out, int out_size, void* d_ws, size_t ws_size,
                              hipStream_t stream) {
    const float* x    = (const float*)d_in[0];
    const float* Wih0 = (const float*)d_in[1];
    const float* Whh0 = (const float*)d_in[2];
    const float* bih0 = (const float*)d_in[3];
    const float* bhh0 = (const float*)d_in[4];
    const float* Wih1 = (const float*)d_in[5];
    const float* Whh1 = (const float*)d_in[6];
    const float* bih1 = (const float*)d_in[7];
    const float* bhh1 = (const float*)d_in[8];
    const float* Wih2 = (const float*)d_in[9];
    const float* Whh2 = (const float*)d_in[10];
    const float* bih2 = (const float*)d_in[11];
    const float* bhh2 = (const float*)d_in[12];
    const float* Wout = (const float*)d_in[13];
    const float* bout = (const float*)d_in[14];
    float* out = (float*)d_out;

    const int grid = (B_SZ + GPW - 1) / GPW;   // 683 blocks x 3 waves = 2049 waves
    gru3_waves<<<grid, 192, 0, stream>>>(x, Wih0, Whh0, bih0, bhh0,
                                         Wih1, Whh1, bih1, bhh1,
                                         Wih2, Whh2, bih2, bhh2,
                                         Wout, bout, out);
}

// Round 5
// 601.142 us; speedup vs baseline: 1.5930x; 1.0259x over previous
//
#include <hip/hip_runtime.h>
#include <cstdint>

#define B_SZ 4096
#define T_SZ 1000
#define I_SZ 3
#define H_SZ 10
#define GPW  6            // batch groups per wave (10 lanes each; lanes 60-63 dummy)
#define STRIDE 36         // words per group (3 slots x 12); 144B, 16B-aligned.
                          // bank start per float4 = (4g+12s+4q)%32 -> 7 groups give
                          // starts {0,4,8,12,16,20,24}+c: pairwise-disjoint 4-bank
                          // spans -> ZERO read conflicts.

__device__ __forceinline__ float fsig(float s) {
    float e = __expf(-s);                       // s<<0 -> inf -> rcp 0; s>>0 -> 1
    return __builtin_amdgcn_rcpf(1.0f + e);
}
__device__ __forceinline__ float ftanh(float y) {
    float e2 = __expf(y + y);                   // inf-safe both ends
    return 1.0f - 2.0f * __builtin_amdgcn_rcpf(e2 + 1.0f);
}

// unpack 3 float4 (10 used) into named scalars dst0..dst9
#define U10(dst, q0, q1, q2) \
    const float dst##0=(q0).x, dst##1=(q0).y, dst##2=(q0).z, dst##3=(q0).w, \
                dst##4=(q1).x, dst##5=(q1).y, dst##6=(q1).z, dst##7=(q1).w, \
                dst##8=(q2).x, dst##9=(q2).y;

// one k-step: 15 independent FMAs (3 per accumulator chain, all chains disjoint)
#define K15(k) \
    r0  = fmaf(wh0[0][k], a##k, r0);  z0  = fmaf(wh0[1][k], a##k, z0);  nh0 = fmaf(wh0[2][k], a##k, nh0); \
    ri1 = fmaf(wi1[0][k], a##k, ri1); zi1 = fmaf(wi1[1][k], a##k, zi1); nx1 = fmaf(wi1[2][k], a##k, nx1); \
    rh1 = fmaf(wh1[0][k], b##k, rh1); zh1 = fmaf(wh1[1][k], b##k, zh1); nh1 = fmaf(wh1[2][k], b##k, nh1); \
    ri2 = fmaf(wi2[0][k], b##k, ri2); zi2 = fmaf(wi2[1][k], b##k, zi2); nx2 = fmaf(wi2[2][k], b##k, nx2); \
    rh2 = fmaf(wh2[0][k], c##k, rh2); zh2 = fmaf(wh2[1][k], c##k, zh2); nh2 = fmaf(wh2[2][k], c##k, nh2);

__global__ __launch_bounds__(64, 1) void gru3_ilp(
    const float* __restrict__ x,
    const float* __restrict__ Wih0, const float* __restrict__ Whh0,
    const float* __restrict__ bih0, const float* __restrict__ bhh0,
    const float* __restrict__ Wih1, const float* __restrict__ Whh1,
    const float* __restrict__ bih1, const float* __restrict__ bhh1,
    const float* __restrict__ Wih2, const float* __restrict__ Whh2,
    const float* __restrict__ bih2, const float* __restrict__ bhh2,
    const float* __restrict__ Wout, const float* __restrict__ bout,
    float* __restrict__ out)
{
    __shared__ __align__(16) float lds[7 * STRIDE];

    const int lane  = threadIdx.x;     // block = 1 wave
    const int j     = lane % H_SZ;     // hidden unit 0..9
    const int g     = lane / H_SZ;     // group 0..6 (6 = dummy)
    const int b_raw = blockIdx.x * GPW + g;
    const int b     = b_raw < B_SZ ? b_raw : (B_SZ - 1);

    // ---- weights for this lane's unit j ----
    float wi0[3][I_SZ], wh0[3][H_SZ];
    float wi1[3][H_SZ], wh1[3][H_SZ];
    float wi2[3][H_SZ], wh2[3][H_SZ];
#pragma unroll
    for (int gg = 0; gg < 3; ++gg) {
        const int row = gg * H_SZ + j;
#pragma unroll
        for (int i = 0; i < I_SZ; ++i) wi0[gg][i] = Wih0[row * I_SZ + i];
#pragma unroll
        for (int k = 0; k < H_SZ; ++k) wh0[gg][k] = Whh0[row * H_SZ + k];
#pragma unroll
        for (int k = 0; k < H_SZ; ++k) wi1[gg][k] = Wih1[row * H_SZ + k];
#pragma unroll
        for (int k = 0; k < H_SZ; ++k) wh1[gg][k] = Whh1[row * H_SZ + k];
#pragma unroll
        for (int k = 0; k < H_SZ; ++k) wi2[gg][k] = Wih2[row * H_SZ + k];
#pragma unroll
        for (int k = 0; k < H_SZ; ++k) wh2[gg][k] = Whh2[row * H_SZ + k];
    }
    // PIN weights in VGPRs: the opaque asm makes each value non-rematerializable,
    // so the compiler cannot sink the global loads back into the 1000-iter loop
    // (R2 evidence: 159 live weights but VGPR_Count=112 -> it was reloading).
#pragma unroll
    for (int gg = 0; gg < 3; ++gg) {
#pragma unroll
        for (int i = 0; i < I_SZ; ++i) asm volatile("" : "+v"(wi0[gg][i]));
#pragma unroll
        for (int k = 0; k < H_SZ; ++k) {
            asm volatile("" : "+v"(wh0[gg][k]));
            asm volatile("" : "+v"(wi1[gg][k]));
            asm volatile("" : "+v"(wh1[gg][k]));
            asm volatile("" : "+v"(wi2[gg][k]));
            asm volatile("" : "+v"(wh2[gg][k]));
        }
    }

    const float br0 = bih0[j] + bhh0[j], bz0 = bih0[H_SZ + j] + bhh0[H_SZ + j];
    const float bni0 = bih0[2 * H_SZ + j], bnh0 = bhh0[2 * H_SZ + j];
    const float br1 = bih1[j] + bhh1[j], bz1 = bih1[H_SZ + j] + bhh1[H_SZ + j];
    const float bni1 = bih1[2 * H_SZ + j], bnh1 = bhh1[2 * H_SZ + j];
    const float br2 = bih2[j] + bhh2[j], bz2 = bih2[H_SZ + j] + bhh2[H_SZ + j];
    const float bni2 = bih2[2 * H_SZ + j], bnh2 = bhh2[2 * H_SZ + j];

    const int gb = g * STRIDE;
    lds[gb + j]      = 0.0f;           // h0 slot
    lds[gb + 12 + j] = 0.0f;           // h1 slot
    lds[gb + 24 + j] = 0.0f;           // h2 slot
    float y0 = 0.0f, y1 = 0.0f, y2 = 0.0f;   // this lane's own h elements

    const float* xp = x + (size_t)b * (T_SZ * I_SZ);
    float cx0 = xp[0], cx1 = xp[1], cx2 = xp[2];   // x[t] for current iter

    const float4* pa = reinterpret_cast<const float4*>(&lds[gb]);
    const float4* pb = reinterpret_cast<const float4*>(&lds[gb + 12]);
    const float4* pc = reinterpret_cast<const float4*>(&lds[gb + 24]);

    float4 Aq0 = pa[0], Aq1 = pa[1], Aq2 = pa[2];   // h0(t-1)
    float4 Bq0 = pb[0], Bq1 = pb[1], Bq2 = pb[2];   // h1(t-2)
    float4 Cq0 = pc[0], Cq1 = pc[1], Cq2 = pc[2];   // h2(t-3)

    // iter it: L0@t=it, L1@t=it-1, L2@t=it-2 (layer-pipelined, barrier-free,
    // single wave). Dots run unconditionally; commits are branch-free selects.
#pragma unroll 1
    for (int it = 0; it < T_SZ + 2; ++it) {
        U10(a, Aq0, Aq1, Aq2)
        U10(b, Bq0, Bq1, Bq2)
        U10(c, Cq0, Cq1, Cq2)

        const float x0 = cx0, x1 = cx1, x2 = cx2;
        const int tn = (it + 1 < T_SZ) ? it + 1 : (T_SZ - 1);
        cx0 = xp[tn * 3 + 0];          // prefetch next x under this body
        cx1 = xp[tn * 3 + 1];
        cx2 = xp[tn * 3 + 2];

        // ---- 16 independent accumulator chains ----
        float r0 = br0, z0 = bz0, nx0 = bni0, nh0 = bnh0;
        float ri1 = br1, rh1 = 0.f, zi1 = bz1, zh1 = 0.f, nx1 = bni1, nh1 = bnh1;
        float ri2 = br2, rh2 = 0.f, zi2 = bz2, zh2 = 0.f, nx2 = bni2, nh2 = bnh2;

        // L0 x-dot (chains r0,z0,nx0 continue below -> depth <=13)
        r0  = fmaf(wi0[0][0], x0, r0);  r0  = fmaf(wi0[0][1], x1, r0);  r0  = fmaf(wi0[0][2], x2, r0);
        z0  = fmaf(wi0[1][0], x0, z0);  z0  = fmaf(wi0[1][1], x1, z0);  z0  = fmaf(wi0[1][2], x2, z0);
        nx0 = fmaf(wi0[2][0], x0, nx0); nx0 = fmaf(wi0[2][1], x1, nx0); nx0 = fmaf(wi0[2][2], x2, nx0);

        K15(0) K15(1) K15(2) K15(3) K15(4)
        K15(5) K15(6) K15(7) K15(8) K15(9)

        const float ar1 = ri1 + rh1, az1 = zi1 + zh1;
        const float ar2 = ri2 + rh2, az2 = zi2 + zh2;

        // ---- transcendental stage: 3 layers' chains independent ----
        const float R0 = fsig(r0),  Z0 = fsig(z0);
        const float R1 = fsig(ar1), Z1 = fsig(az1);
        const float R2 = fsig(ar2), Z2 = fsig(az2);
        const float N0 = ftanh(fmaf(R0, nh0, nx0));
        const float N1 = ftanh(fmaf(R1, nh1, nx1));
        const float N2 = ftanh(fmaf(R2, nh2, nx2));

        const float y0n = fmaf(Z0, y0 - N0, N0);
        const float y1n = fmaf(Z1, y1 - N1, N1);
        const float y2n = fmaf(Z2, y2 - N2, N2);

        // branch-free commit (inactive pipeline phases keep old h)
        y0 = (it < T_SZ)                 ? y0n : y0;
        y1 = (it >= 1 && it <= T_SZ)     ? y1n : y1;
        y2 = (it >= 2)                   ? y2n : y2;

        lds[gb + j]      = y0;
        lds[gb + 12 + j] = y1;
        lds[gb + 24 + j] = y2;

        // rotate: next iteration's h reads issue under the loop tail
        Aq0 = pa[0]; Aq1 = pa[1]; Aq2 = pa[2];
        Bq0 = pb[0]; Bq1 = pb[1]; Bq2 = pb[2];
        Cq0 = pc[0]; Cq1 = pc[1]; Cq2 = pc[2];
    }

    // ---- output projection: out[b] = h2(T-1) . Wout + bout ----
    if (j == 0 && g < GPW && b_raw < B_SZ) {
        const float* hv = &lds[gb + 24];
        float acc = bout[0];
#pragma unroll
        for (int k = 0; k < H_SZ; ++k) acc = fmaf(hv[k], Wout[k], acc);
        out[b_raw] = acc;
    }
}

extern "C" void kernel_launch(void* const* d_in, const int* in_sizes, int n_in,
                              void* d_out, int out_size, void* d_ws, size_t ws_size,
                              hipStream_t stream) {
    const float* x    = (const float*)d_in[0];
    const float* Wih0 = (const float*)d_in[1];
    const float* Whh0 = (const float*)d_in[2];
    const float* bih0 = (const float*)d_in[3];
    const float* bhh0 = (const float*)d_in[4];
    const float* Wih1 = (const float*)d_in[5];
    const float* Whh1 = (const float*)d_in[6];
    const float* bih1 = (const float*)d_in[7];
    const float* bhh1 = (const float*)d_in[8];
    const float* Wih2 = (const float*)d_in[9];
    const float* Whh2 = (const float*)d_in[10];
    const float* bih2 = (const float*)d_in[11];
    const float* bhh2 = (const float*)d_in[12];
    const float* Wout = (const float*)d_in[13];
    const float* bout = (const float*)d_in[14];
    float* out = (float*)d_out;

    const int grid = (B_SZ + GPW - 1) / GPW;   // 683 single-wave blocks
    gru3_ilp<<<grid, 64, 0, stream>>>(x, Wih0, Whh0, bih0, bhh0,
                                      Wih1, Whh1, bih1, bhh1,
                                      Wih2, Whh2, bih2, bhh2,
                                      Wout, bout, out);
}